// Round 1
// baseline (1415.428 us; speedup 1.0000x reference)
//
#include <hip/hip_runtime.h>
#include <hip/hip_bf16.h>

// NodeNetwork: mi = segsum(ea*x[row] -> col), mo = segsum(ea*x[col] -> row)
// out = tanh(tanh([mi|mo|x] @ W1 + b1) @ W2 + b2)
// N=100000, D=32, O=64, E=1600000

#define DFEAT 32
#define OFEAT 64

// ---------------- edge scatter: 8 lanes per edge, float4 per lane ----------
__global__ __launch_bounds__(256) void edge_scatter_kernel(
    const float* __restrict__ x,      // [N,32]
    const int*   __restrict__ ei,     // [2,E]
    const float* __restrict__ ea,     // [E]
    float* __restrict__ mi,           // [N,32] accum (dest = col)
    float* __restrict__ mo,           // [N,32] accum (dest = row)
    int E)
{
    long long tid = (long long)blockIdx.x * blockDim.x + threadIdx.x;
    long long total = (long long)E * 8;
    if (tid >= total) return;
    int e = (int)(tid >> 3);
    int q = (int)(tid & 7);          // which float4 chunk (0..7) of the 32 feats

    int r = ei[e];                   // row (source for mi, dest for mo)
    int c = ei[E + e];               // col (dest for mi, source for mo)
    float a = ea[e];

    const float4* x4 = (const float4*)x;
    float4 xr = x4[(long long)r * 8 + q];
    float4 xc = x4[(long long)c * 8 + q];

    float* mip = mi + (long long)c * DFEAT + q * 4;
    float* mop = mo + (long long)r * DFEAT + q * 4;

    atomicAdd(mip + 0, a * xr.x);
    atomicAdd(mip + 1, a * xr.y);
    atomicAdd(mip + 2, a * xr.z);
    atomicAdd(mip + 3, a * xr.w);
    atomicAdd(mop + 0, a * xc.x);
    atomicAdd(mop + 1, a * xc.y);
    atomicAdd(mop + 2, a * xc.z);
    atomicAdd(mop + 3, a * xc.w);
}

// ---------------- fused MLP: 4 nodes per group, 1 wave per node ------------
// block = 256 threads = 4 waves; wave w handles node group_base+w, lane = out idx
__global__ __launch_bounds__(256) void mlp_kernel(
    const float* __restrict__ mi,
    const float* __restrict__ mo,
    const float* __restrict__ x,
    const float* __restrict__ W1,   // [96,64] row-major (in,out)
    const float* __restrict__ b1,   // [64]
    const float* __restrict__ W2,   // [64,64]
    const float* __restrict__ b2,   // [64]
    float* __restrict__ out,        // [N,64]
    int N, int ngroups)
{
    __shared__ float sW1[96 * 64];   // 24 KB
    __shared__ float sW2[64 * 64];   // 16 KB
    __shared__ float sM[4][96];      // per-group input rows
    __shared__ float sh[4][64];      // hidden activations

    // stage weights once per block
    for (int i = threadIdx.x; i < 96 * 64; i += 256) sW1[i] = W1[i];
    for (int i = threadIdx.x; i < 64 * 64; i += 256) sW2[i] = W2[i];
    __syncthreads();

    int nl = threadIdx.x >> 6;       // 0..3: which node in group (== wave id)
    int o  = threadIdx.x & 63;       // output index 0..63
    float bias1 = b1[o];
    float bias2 = b2[o];

    for (int g = blockIdx.x; g < ngroups; g += gridDim.x) {
        int node0 = g * 4;
        // stage M = [mi | mo | x] for 4 nodes (384 floats)
        for (int i = threadIdx.x; i < 4 * 96; i += 256) {
            int n_local = i / 96;
            int k = i - n_local * 96;
            int node = node0 + n_local;
            float v = 0.0f;
            if (node < N) {
                if (k < 32)       v = mi[(long long)node * 32 + k];
                else if (k < 64)  v = mo[(long long)node * 32 + (k - 32)];
                else              v = x [(long long)node * 32 + (k - 64)];
            }
            sM[n_local][k] = v;
        }
        __syncthreads();

        // layer 1: h = tanh(M @ W1 + b1)
        float acc = bias1;
        #pragma unroll
        for (int k = 0; k < 96; ++k)
            acc = fmaf(sM[nl][k], sW1[k * 64 + o], acc);
        sh[nl][o] = tanhf(acc);
        __syncthreads();

        // layer 2: out = tanh(h @ W2 + b2)
        float acc2 = bias2;
        #pragma unroll
        for (int k = 0; k < 64; ++k)
            acc2 = fmaf(sh[nl][k], sW2[k * 64 + o], acc2);

        int node = node0 + nl;
        if (node < N)
            out[(long long)node * 64 + o] = tanhf(acc2);
        // no extra sync needed here: next iteration's sM write happens after
        // the __syncthreads() above in each thread's program order... but the
        // first sM write of iter g+1 is only separated from iter g's sh reads
        // by distinct buffers (sM vs sh); sh rewrite is after next sync. Safe.
        __syncthreads();
    }
}

extern "C" void kernel_launch(void* const* d_in, const int* in_sizes, int n_in,
                              void* d_out, int out_size, void* d_ws, size_t ws_size,
                              hipStream_t stream) {
    const float* x  = (const float*)d_in[0];
    const int*   ei = (const int*)  d_in[1];
    const float* ea = (const float*)d_in[2];
    const float* W1 = (const float*)d_in[3];
    const float* b1 = (const float*)d_in[4];
    const float* W2 = (const float*)d_in[5];
    const float* b2 = (const float*)d_in[6];
    float* out = (float*)d_out;

    int N = in_sizes[0] / DFEAT;     // 100000
    int E = in_sizes[2];             // 1600000 (edge_attr is [E,1])

    float* mi = (float*)d_ws;
    float* mo = mi + (size_t)N * DFEAT;

    // zero accumulators (required every call: atomics accumulate)
    hipMemsetAsync(d_ws, 0, (size_t)N * DFEAT * 2 * sizeof(float), stream);

    // edge scatter
    long long total = (long long)E * 8;
    int blk = 256;
    int nblocks = (int)((total + blk - 1) / blk);
    edge_scatter_kernel<<<nblocks, blk, 0, stream>>>(x, ei, ea, mi, mo, E);

    // fused MLP
    int ngroups = (N + 3) / 4;
    int mlpblocks = ngroups < 2048 ? ngroups : 2048;
    mlp_kernel<<<mlpblocks, 256, 0, stream>>>(mi, mo, x, W1, b1, W2, b2, out, N, ngroups);
}

// Round 2
// 686.795 us; speedup vs baseline: 2.0609x; 2.0609x over previous
//
#include <hip/hip_runtime.h>
#include <hip/hip_bf16.h>

// NodeNetwork: mi = segsum(ea*x[row] -> col), mo = segsum(ea*x[col] -> row)
// out = tanh(tanh([mi|mo|x] @ W1 + b1) @ W2 + b2)
// N=100000, D=32, O=64, E=1600000
//
// R2 strategy: replace 102.4M float atomics (80 G/s atomic-pipe ceiling, R1
// profile) with counting-sort-by-destination + atomic-free wave gather.

#define DFEAT 32
#define OFEAT 64

// ===================== R2 path: counting sort + gather =====================

// ---- 1. histogram of destinations: key = 2*dest + flag (flag 0 = mi, 1 = mo)
__global__ __launch_bounds__(256) void hist_kernel(
    const int* __restrict__ ei, int* __restrict__ cnt, int E)
{
    int e = blockIdx.x * 256 + threadIdx.x;
    if (e >= E) return;
    int r = ei[e];
    int c = ei[E + e];
    atomicAdd(&cnt[2 * c + 0], 1);   // mi segment of node c
    atomicAdd(&cnt[2 * r + 1], 1);   // mo segment of node r
}

// ---- 2a. per-block reduce (256 elems/block)
__global__ __launch_bounds__(256) void scan_reduce(
    const int* __restrict__ cnt, int* __restrict__ bsum, int M)
{
    __shared__ int s[256];
    int i = blockIdx.x * 256 + threadIdx.x;
    s[threadIdx.x] = (i < M) ? cnt[i] : 0;
    __syncthreads();
    for (int st = 128; st > 0; st >>= 1) {
        if (threadIdx.x < st) s[threadIdx.x] += s[threadIdx.x + st];
        __syncthreads();
    }
    if (threadIdx.x == 0) bsum[blockIdx.x] = s[0];
}

// ---- 2b. single-block exclusive scan of block sums (nb <= 1024)
__global__ __launch_bounds__(1024) void scan_bsums(int* __restrict__ bsum, int nb)
{
    __shared__ int s[1024];
    int t = threadIdx.x;
    s[t] = (t < nb) ? bsum[t] : 0;
    __syncthreads();
    for (int off = 1; off < 1024; off <<= 1) {
        int v = (t >= off) ? s[t - off] : 0;
        __syncthreads();
        s[t] += v;
        __syncthreads();
    }
    if (t < nb) bsum[t] = (t == 0) ? 0 : s[t - 1];
}

// ---- 2c. per-block scan + add block prefix -> off (and cursor copy cur)
__global__ __launch_bounds__(256) void scan_final(
    const int* __restrict__ cnt, const int* __restrict__ bsum,
    int* __restrict__ off, int* __restrict__ cur, int M)
{
    __shared__ int s[256];
    int i = blockIdx.x * 256 + threadIdx.x;
    int v = (i < M) ? cnt[i] : 0;
    s[threadIdx.x] = v;
    __syncthreads();
    for (int o = 1; o < 256; o <<= 1) {
        int u = (threadIdx.x >= o) ? s[threadIdx.x - o] : 0;
        __syncthreads();
        s[threadIdx.x] += u;
        __syncthreads();
    }
    int excl = s[threadIdx.x] - v + bsum[blockIdx.x];
    if (i < M) { off[i] = excl; cur[i] = excl; }
}

// ---- 3. scatter packed (src, attr) payloads into segments (ticket atomics)
__global__ __launch_bounds__(256) void scatter_kernel(
    const int* __restrict__ ei, const float* __restrict__ ea,
    int* __restrict__ cur, int2* __restrict__ pay, int E)
{
    int e = blockIdx.x * 256 + threadIdx.x;
    if (e >= E) return;
    int r = ei[e];
    int c = ei[E + e];
    int ai = __float_as_int(ea[e]);
    int p0 = atomicAdd(&cur[2 * c + 0], 1);   // mi: src = r
    pay[p0] = make_int2(r, ai);
    int p1 = atomicAdd(&cur[2 * r + 1], 1);   // mo: src = c
    pay[p1] = make_int2(c, ai);
}

// ---- 4. gather: one wave per segment key k in [0, 2N); no atomics
__global__ __launch_bounds__(256) void gather_kernel(
    const float* __restrict__ x,
    const int* __restrict__ off, const int* __restrict__ cnt,
    const int2* __restrict__ pay,
    float* __restrict__ mi, float* __restrict__ mo, int NK)
{
    int k = (blockIdx.x * 256 + threadIdx.x) >> 6;   // global wave id = key
    if (k >= NK) return;
    int lane = threadIdx.x & 63;
    int feat = lane & 31;
    int half = lane >> 5;

    int s = off[k];
    int c = cnt[k];
    float acc = 0.0f;
    for (int i = s + half; i < s + c; i += 2) {
        int2 p = pay[i];                               // broadcast 8B load
        acc += __int_as_float(p.y) * x[(long long)p.x * DFEAT + feat];
    }
    acc += __shfl_xor(acc, 32, 64);
    if (half == 0) {
        int node = k >> 1;
        float* dst = (k & 1) ? mo : mi;
        dst[(long long)node * DFEAT + feat] = acc;
    }
}

// ===================== R1 fallback: direct atomic scatter ==================
__global__ __launch_bounds__(256) void edge_scatter_kernel(
    const float* __restrict__ x, const int* __restrict__ ei,
    const float* __restrict__ ea,
    float* __restrict__ mi, float* __restrict__ mo, int E)
{
    long long tid = (long long)blockIdx.x * blockDim.x + threadIdx.x;
    long long total = (long long)E * 8;
    if (tid >= total) return;
    int e = (int)(tid >> 3);
    int q = (int)(tid & 7);
    int r = ei[e];
    int c = ei[E + e];
    float a = ea[e];
    const float4* x4 = (const float4*)x;
    float4 xr = x4[(long long)r * 8 + q];
    float4 xc = x4[(long long)c * 8 + q];
    float* mip = mi + (long long)c * DFEAT + q * 4;
    float* mop = mo + (long long)r * DFEAT + q * 4;
    atomicAdd(mip + 0, a * xr.x); atomicAdd(mip + 1, a * xr.y);
    atomicAdd(mip + 2, a * xr.z); atomicAdd(mip + 3, a * xr.w);
    atomicAdd(mop + 0, a * xc.x); atomicAdd(mop + 1, a * xc.y);
    atomicAdd(mop + 2, a * xc.z); atomicAdd(mop + 3, a * xc.w);
}

// ===================== fused MLP (unchanged from R1, passing) ==============
__global__ __launch_bounds__(256) void mlp_kernel(
    const float* __restrict__ mi, const float* __restrict__ mo,
    const float* __restrict__ x,
    const float* __restrict__ W1, const float* __restrict__ b1,
    const float* __restrict__ W2, const float* __restrict__ b2,
    float* __restrict__ out, int N, int ngroups)
{
    __shared__ float sW1[96 * 64];
    __shared__ float sW2[64 * 64];
    __shared__ float sM[4][96];
    __shared__ float sh[4][64];

    for (int i = threadIdx.x; i < 96 * 64; i += 256) sW1[i] = W1[i];
    for (int i = threadIdx.x; i < 64 * 64; i += 256) sW2[i] = W2[i];
    __syncthreads();

    int nl = threadIdx.x >> 6;
    int o  = threadIdx.x & 63;
    float bias1 = b1[o];
    float bias2 = b2[o];

    for (int g = blockIdx.x; g < ngroups; g += gridDim.x) {
        int node0 = g * 4;
        for (int i = threadIdx.x; i < 4 * 96; i += 256) {
            int n_local = i / 96;
            int kk = i - n_local * 96;
            int node = node0 + n_local;
            float v = 0.0f;
            if (node < N) {
                if (kk < 32)      v = mi[(long long)node * 32 + kk];
                else if (kk < 64) v = mo[(long long)node * 32 + (kk - 32)];
                else              v = x [(long long)node * 32 + (kk - 64)];
            }
            sM[n_local][kk] = v;
        }
        __syncthreads();

        float acc = bias1;
        #pragma unroll
        for (int kk = 0; kk < 96; ++kk)
            acc = fmaf(sM[nl][kk], sW1[kk * 64 + o], acc);
        sh[nl][o] = tanhf(acc);
        __syncthreads();

        float acc2 = bias2;
        #pragma unroll
        for (int kk = 0; kk < 64; ++kk)
            acc2 = fmaf(sh[nl][kk], sW2[kk * 64 + o], acc2);

        int node = node0 + nl;
        if (node < N)
            out[(long long)node * 64 + o] = tanhf(acc2);
        __syncthreads();
    }
}

extern "C" void kernel_launch(void* const* d_in, const int* in_sizes, int n_in,
                              void* d_out, int out_size, void* d_ws, size_t ws_size,
                              hipStream_t stream) {
    const float* x  = (const float*)d_in[0];
    const int*   ei = (const int*)  d_in[1];
    const float* ea = (const float*)d_in[2];
    const float* W1 = (const float*)d_in[3];
    const float* b1 = (const float*)d_in[4];
    const float* W2 = (const float*)d_in[5];
    const float* b2 = (const float*)d_in[6];
    float* out = (float*)d_out;

    int N = in_sizes[0] / DFEAT;     // 100000
    int E = in_sizes[2];             // 1600000
    int M = 2 * N;                   // number of segments (node x direction)

    float* mi = (float*)d_ws;
    float* mo = mi + (size_t)N * DFEAT;

    size_t need = (size_t)N * DFEAT * 2 * 4     // mi, mo
                + (size_t)M * 3 * 4 + 4096      // cnt, off, cur, bsum
                + (size_t)2 * E * 8;            // payload
    if (ws_size >= need) {
        int* cnt  = (int*)(mo + (size_t)N * DFEAT);
        int* off  = cnt + M;
        int* cur  = off + M;
        int* bsum = cur + M;
        int2* pay = (int2*)(bsum + 1024);

        hipMemsetAsync(cnt, 0, (size_t)M * sizeof(int), stream);

        int eblk = (E + 255) / 256;
        hist_kernel<<<eblk, 256, 0, stream>>>(ei, cnt, E);

        int nb = (M + 255) / 256;                 // 782 <= 1024
        scan_reduce<<<nb, 256, 0, stream>>>(cnt, bsum, M);
        scan_bsums<<<1, 1024, 0, stream>>>(bsum, nb);
        scan_final<<<nb, 256, 0, stream>>>(cnt, bsum, off, cur, M);

        scatter_kernel<<<eblk, 256, 0, stream>>>(ei, ea, cur, pay, E);

        int gblk = (M + 3) / 4;                   // wave per segment, 4/block
        gather_kernel<<<gblk, 256, 0, stream>>>(x, off, cnt, pay, mi, mo, M);
    } else {
        // fallback: R1 atomic path
        hipMemsetAsync(d_ws, 0, (size_t)N * DFEAT * 2 * sizeof(float), stream);
        long long total = (long long)E * 8;
        int nblocks = (int)((total + 255) / 256);
        edge_scatter_kernel<<<nblocks, 256, 0, stream>>>(x, ei, ea, mi, mo, E);
    }

    int ngroups = (N + 3) / 4;
    int mlpblocks = ngroups < 2048 ? ngroups : 2048;
    mlp_kernel<<<mlpblocks, 256, 0, stream>>>(mi, mo, x, W1, b1, W2, b2, out, N, ngroups);
}